// Round 7
// baseline (487.826 us; speedup 1.0000x reference)
//
#include <hip/hip_runtime.h>

// LSTM B=2048,T=512,I=5,H=128 + linear -> [B,1], fp32 in/out.
// Round 19: DESYNC CO-BLOCKS. BT=4, NT=256, grid=512 -> 2 blocks/CU with
// INDEPENDENT barriers. Each wave owns 32 gate-cols (2 chunks); chunk1's
// gate-args are shfl_xor(32)'d to the upper half-wave so all 64 lanes run
// real activation chains (trans stays at the algorithmic-min 20/wave/step).
// WHY: r13-r16 proved the ~570cy/step residue (ds latency + trans chains +
// barrier lockstep) cannot be scheduled away inside one barrier-locked
// block; r18 proved SGBs are neutral-to-negative on the i8 dataflow (r17
// 285us > r18 292us) -> NO SGBs here. The only agent that can fill a
// barrier-locked residue is a second block with its own barrier. BT=4 was
// dismissed as "doubles MFMA padding (modeled)" when MFMA was 47% of the
// step; at 27% (i8) the trade flips: MFMA issue 364->~716cy/SIMD overlays
// two step-streams that hide each other's residue.
// PREDICTED: dispatch 215-250us, MfmaUtil 55-70%, VGPR 160-200, WG 256,
// grid 512, LDS ~40KB, absmax EXACTLY 0.0009765625 (per-value DAG
// unchanged). Failure mode (~320-350us, MfmaUtil ~45%) = blocks lockstep;
// then r17 is the proven ceiling.
// Proven/unchanged: i8 h-matmul (W*1024, h*127, exact i32 accum), f16 K=16
// x/bias MFMA sc-baked, row permutation rho(b)=(b>>1)*4+(b&1), dbuf h + 1
// barrier/step, peeled last step, folded activation scales.
// Dead-ends: BT=16 halves CUs; 1024-thr 8-col tiles; K-split LDS exchange
// (r7); VALU pin between dependent MFMA groups (r13); chain split (r14);
// MF16 hoist (r15); 1 wave/SIMD same-block (r16: conflicts halved exactly
// as predicted, latency exposed, +18%); SGB on i8 dataflow (r18).

#define HH 128
#define II 5
#define TT 512
#define BT 4
#define NT 256
#define K8S 144            // hb8 row stride in bytes
#define HB8 (16 * K8S)     // hb8 buffer stride in bytes
#define KS 136             // zrow stride in f16 (x path)
#define XT (TT * 8 + 8)    // xs per-batch stride in f16

typedef __attribute__((ext_vector_type(4))) _Float16 half4;
typedef __attribute__((ext_vector_type(4))) float f32x4;
typedef __attribute__((ext_vector_type(4))) int int4v;

#define SIG(u) __builtin_amdgcn_rcpf(1.0f + __builtin_amdgcn_exp2f(u))
#define MF16(A, B, C) __builtin_amdgcn_mfma_f32_16x16x16f16((A), (B), (C), 0, 0, 0)
#define MI8(A, B, C)  __builtin_amdgcn_mfma_i32_16x16x64_i8((A), (B), (C), 0, 0, 0)

// Recombine scales: arg = xp + S * (sc_g / (1024*127))
#define INV_IFO (-1.44269504f / 130048.0f)
#define INV_G   ( 2.88539008f / 130048.0f)

// One timestep. PB = h read buffer (compile-time 0/1), LAST = peeled final.
// Chunk 0 args stay in lower half-wave (q=0,1); chunk 1 args are computed
// there too (their D rows live there) and shfl_xor(32)'d to the upper half.
#define STEP(PB, LAST) {                                                        \
    const unsigned char* hp = hrd8 + (PB) * HB8;                                \
    int4v alo = *reinterpret_cast<const int4v*>(hp);                            \
    int4v ahi = *reinterpret_cast<const int4v*>(hp + 64);                       \
    /* x/bias projection, f16 K=16, sc-baked (register-only: ds cover) */       \
    f32x4 xp00 = MF16(ax4, wfx[0][0], zero4);                                   \
    f32x4 xp01 = MF16(ax4, wfx[0][1], zero4);                                   \
    f32x4 xp02 = MF16(ax4, wfx[0][2], zero4);                                   \
    f32x4 xp03 = MF16(ax4, wfx[0][3], zero4);                                   \
    f32x4 xp10 = MF16(ax4, wfx[1][0], zero4);                                   \
    f32x4 xp11 = MF16(ax4, wfx[1][1], zero4);                                   \
    f32x4 xp12 = MF16(ax4, wfx[1][2], zero4);                                   \
    f32x4 xp13 = MF16(ax4, wfx[1][3], zero4);                                   \
    if (!(LAST)) {                      /* prefetch ax(t+1): static xs */       \
        xcur += xinc;                                                           \
        ax4 = *reinterpret_cast<const half4*>(xcur);                            \
    }                                                                           \
    /* i,f MI8 chains, both chunks (K=64 x2, exact i32) */                      \
    int4v s00 = MI8(alo, wq[0][0][0], zeroi);                                   \
    int4v s01 = MI8(alo, wq[0][1][0], zeroi);                                   \
    int4v s10 = MI8(alo, wq[1][0][0], zeroi);                                   \
    int4v s11 = MI8(alo, wq[1][1][0], zeroi);                                   \
    s00 = MI8(ahi, wq[0][0][1], s00);                                           \
    s01 = MI8(ahi, wq[0][1][1], s01);                                           \
    s10 = MI8(ahi, wq[1][0][1], s10);                                           \
    s11 = MI8(ahi, wq[1][1][1], s11);                                           \
    /* recombine i,f; move chunk1 args to the upper half-wave */                \
    float ai0 = fmaf((float)s00[0], INV_IFO, xp00[0]);                          \
    float ai1 = fmaf((float)s00[1], INV_IFO, xp00[1]);                          \
    float af0 = fmaf((float)s01[0], INV_IFO, xp01[0]);                          \
    float af1 = fmaf((float)s01[1], INV_IFO, xp01[1]);                          \
    float bi0 = __shfl_xor(fmaf((float)s10[0], INV_IFO, xp10[0]), 32, 64);      \
    float bi1 = __shfl_xor(fmaf((float)s10[1], INV_IFO, xp10[1]), 32, 64);      \
    float bf0 = __shfl_xor(fmaf((float)s11[0], INV_IFO, xp11[0]), 32, 64);      \
    float bf1 = __shfl_xor(fmaf((float)s11[1], INV_IFO, xp11[1]), 32, 64);      \
    float iv0 = SIG(hi ? bi0 : ai0);                                            \
    float iv1 = SIG(hi ? bi1 : ai1);                                            \
    float fv0 = SIG(hi ? bf0 : af0);                                            \
    float fv1 = SIG(hi ? bf1 : af1);                                            \
    /* g,o MI8 chains, both chunks */                                           \
    int4v s02 = MI8(alo, wq[0][2][0], zeroi);                                   \
    int4v s03 = MI8(alo, wq[0][3][0], zeroi);                                   \
    int4v s12 = MI8(alo, wq[1][2][0], zeroi);                                   \
    int4v s13 = MI8(alo, wq[1][3][0], zeroi);                                   \
    s02 = MI8(ahi, wq[0][2][1], s02);                                           \
    s03 = MI8(ahi, wq[0][3][1], s03);                                           \
    s12 = MI8(ahi, wq[1][2][1], s12);                                           \
    s13 = MI8(ahi, wq[1][3][1], s13);                                           \
    float ag0 = fmaf((float)s02[0], INV_G,   xp02[0]);                          \
    float ag1 = fmaf((float)s02[1], INV_G,   xp02[1]);                          \
    float ao0 = fmaf((float)s03[0], INV_IFO, xp03[0]);                          \
    float ao1 = fmaf((float)s03[1], INV_IFO, xp03[1]);                          \
    float bg0 = __shfl_xor(fmaf((float)s12[0], INV_G,   xp12[0]), 32, 64);      \
    float bg1 = __shfl_xor(fmaf((float)s12[1], INV_G,   xp12[1]), 32, 64);      \
    float bo0 = __shfl_xor(fmaf((float)s13[0], INV_IFO, xp13[0]), 32, 64);      \
    float bo1 = __shfl_xor(fmaf((float)s13[1], INV_IFO, xp13[1]), 32, 64);      \
    float gv0 = 1.0f - 2.0f * SIG(hi ? bg0 : ag0);                              \
    float ov0 = SIG(hi ? bo0 : ao0);                                            \
    cc0 = fv0 * cc0 + iv0 * gv0;                                                \
    float hv0 = ov0 * (1.0f - 2.0f * SIG(2.88539008f * cc0));                   \
    float gv1 = 1.0f - 2.0f * SIG(hi ? bg1 : ag1);                              \
    float ov1 = SIG(hi ? bo1 : ao1);                                            \
    cc1 = fv1 * cc1 + iv1 * gv1;                                                \
    float hv1 = ov1 * (1.0f - 2.0f * SIG(2.88539008f * cc1));                   \
    if (LAST) {                                                                 \
        hsc[bcell][mycol] = hv0; hsc[bcell + 1][mycol] = hv1;                   \
    } else {                                                                    \
        unsigned char* wp = hwr8 + ((PB) ^ 1) * HB8;                            \
        wp[0]    = (unsigned char)(signed char)(int)rintf(hv0 * 127.0f);        \
        wp[K8S]  = (unsigned char)(signed char)(int)rintf(hv1 * 127.0f);        \
    }                                                                           \
    __syncthreads();                                                            \
}

__global__ __launch_bounds__(NT)
__attribute__((amdgpu_waves_per_eu(2, 2)))   // 2 waves/EU (one per block): 256-VGPR budget
void lstm_r19(const float* __restrict__ x,      // [B,T,I]
              const float* __restrict__ W_ih,   // [4H,I]
              const float* __restrict__ W_hh,   // [4H,H]
              const float* __restrict__ b_ih,   // [4H]
              const float* __restrict__ b_hh,   // [4H]
              const float* __restrict__ W_lin,  // [H]
              const float* __restrict__ b_lin,  // [1]
              float* __restrict__ out,          // [B]
              int B)
{
    __shared__ __align__(16) unsigned char hb8[2][16][K8S]; // h as i8; pad rows 0
    __shared__ __align__(16) _Float16 zrow[KS];         // zeros for pad-row x lanes
    __shared__ __align__(16) _Float16 xs[BT * XT];      // 32.8 KB staged x (f16)
    __shared__ float hsc[BT][HH + 4];                   // final fp32 h

    const int tid  = threadIdx.x;
    const int b0   = blockIdx.x * BT;
    const int lane = tid & 63;
    const int w    = tid >> 6;        // 0..3 -> 32-col group
    const int n    = lane & 15;       // A row index / D col
    const int q    = lane >> 4;
    const bool hi  = (q >= 2);        // upper half-wave processes chunk 1
    const int qr   = q & 1;           // batch-pair index post-swap
    const int mycol = w * 32 + (hi ? 16 : 0) + n;   // col this lane OWNS

    // ---- W_hh as i8, B-layout: lane holds W^T[k][col] for k=q*16+e (lo) ----
    // and k=64+q*16+e (hi half), packed 4 bytes/i32. scale 1024.
    int4v wq[2][4][2];                // [chunk][gate][half]
    half4 wfx[2][4];                  // x/bias f16, K=16, sc-baked
    #pragma unroll
    for (int c = 0; c < 2; ++c) {
        #pragma unroll
        for (int g = 0; g < 4; ++g) {
            const float sc = (g == 2) ? 2.88539008f : -1.44269504f;
            const int j = g * HH + w * 32 + c * 16 + n;
            #pragma unroll
            for (int hf = 0; hf < 2; ++hf) {
                const float* p = W_hh + (size_t)j * HH + hf * 64 + q * 16;
                #pragma unroll
                for (int r = 0; r < 4; ++r) {
                    int wd = 0;
                    #pragma unroll
                    for (int u = 0; u < 4; ++u) {
                        int bq = (int)rintf(p[r * 4 + u] * 1024.0f); // |W|*1024<=91
                        wd |= (bq & 0xff) << (8 * u);
                    }
                    wq[c][g][hf][r] = wd;
                }
            }
            #pragma unroll
            for (int e = 0; e < 4; ++e) {
                const int k = q * 4 + e;
                float v = 0.0f;
                if (k < II)       v = W_ih[j * II + k];
                else if (k == II) v = b_ih[j] + b_hh[j];
                wfx[c][g][e] = (_Float16)(v * sc);
            }
        }
    }

    // ---- zero LDS -----------------------------------------------------------
    for (int idx = tid; idx < 2 * 16 * K8S; idx += NT)
        (&hb8[0][0][0])[idx] = 0;
    for (int idx = tid; idx < KS; idx += NT) zrow[idx] = (_Float16)0.0f;
    for (int idx = tid; idx < BT * XT; idx += NT)
        xs[idx] = (_Float16)0.0f;
    __syncthreads();

    // ---- stage x (f16) + constant-1.0 bias column in slot 5 -----------------
    {
        const int lb = tid & 63, bb = tid >> 6;     // 64 threads per batch
        if (b0 + bb < B) {
            const float* xb = x + (size_t)(b0 + bb) * TT * II;
            for (int e = lb * 4; e < TT * II; e += 256) {
                float4 v = *reinterpret_cast<const float4*>(xb + e);
                float vv[4] = {v.x, v.y, v.z, v.w};
                #pragma unroll
                for (int u = 0; u < 4; ++u) {
                    const int ee = e + u;
                    xs[bb * XT + (ee / 5) * 8 + (ee % 5)] = (_Float16)vv[u];
                }
            }
        }
        for (int s = tid; s < BT * TT; s += NT)
            xs[(s >> 9) * XT + (s & 511) * 8 + 5] = (_Float16)1.0f;
    }
    __syncthreads();

    // ---- loop-invariant state ----------------------------------------------
    // Row permutation: batch b -> A-row rho(b) = (b>>1)*4 + (b&1); BT=4 uses
    // rows {0,1,4,5}. Post-swap, lane (n,q) owns cells (mycol, batches
    // 2*qr, 2*qr+1); D rows qr*4+{0,1} of the chunk it owns.
    const int bcell = 2 * qr;
    float cc0 = 0.f, cc1 = 0.f;
    const f32x4 zero4 = {0.f, 0.f, 0.f, 0.f};
    const int4v zeroi = {0, 0, 0, 0};
    // x A-frag: real batch rows {0,1,4,5} only (BT=4)
    const bool xreal = ((n & 2) == 0) && (n < 8);
    const int  bofn  = (n >> 2) * 2 + (n & 1);      // batch carried by A-row n
    // A-frag (i8 K=64): lane (n,q) reads h row n, bytes q*16..+15 (lo), +64 (hi).
    // Rows not in {0,1,4,5} stay zero -> their D rows are never read anyway.
    const unsigned char* hrd8 = &hb8[0][n][0] + q * 16;
    // h write: lane owns (mycol, rows qr*4, qr*4+1) -- all 64 lanes write real h.
    unsigned char*       hwr8 = &hb8[0][qr * 4][0] + mycol;
    const _Float16* xcur = xreal ? (&xs[bofn * XT] + q * 4) : (&zrow[0] + q * 4);
    const int       xinc = xreal ? 8 : 0;

    half4 ax4 = *reinterpret_cast<const half4*>(xcur);   // t=0 preload

    #pragma unroll 1
    for (int k = 0; k < (TT - 2) / 2; ++k) {
        STEP(0, false);
        STEP(1, false);
    }
    STEP(0, false);     // t = 510
    STEP(1, true);      // t = 511, peeled: fp32 hsc write, no prefetch

    // ---- epilogue: out[b0+w] = hsc[w,:] . W_lin + b_lin (wave w = batch w) --
    float p = hsc[w][lane] * W_lin[lane] + hsc[w][lane + 64] * W_lin[lane + 64];
    #pragma unroll
    for (int off = 32; off > 0; off >>= 1) p += __shfl_down(p, off, 64);
    if (lane == 0 && (b0 + w) < B) out[b0 + w] = p + b_lin[0];
}

extern "C" void kernel_launch(void* const* d_in, const int* in_sizes, int n_in,
                              void* d_out, int out_size, void* d_ws, size_t ws_size,
                              hipStream_t stream) {
    const float* x     = (const float*)d_in[0];
    const float* W_ih  = (const float*)d_in[1];
    const float* W_hh  = (const float*)d_in[2];
    const float* b_ih  = (const float*)d_in[3];
    const float* b_hh  = (const float*)d_in[4];
    const float* W_lin = (const float*)d_in[5];
    const float* b_lin = (const float*)d_in[6];
    float* out = (float*)d_out;

    const int B = in_sizes[0] / (TT * II);          // 2048
    const int grid = (B + BT - 1) / BT;             // 512 blocks, 2 per CU
    lstm_r19<<<grid, NT, 0, stream>>>(x, W_ih, W_hh, b_ih, b_hh,
                                      W_lin, b_lin, out, B);
}

// Round 8
// 326.101 us; speedup vs baseline: 1.4959x; 1.4959x over previous
//
#include <hip/hip_runtime.h>

// LSTM B=2048,T=512,I=5,H=128 + linear -> [B,1], fp32 in/out.
// Round 20 = r17 RESTORED VERBATIM (285us dispatch / 325.7us e2e, best;
// absmax 9.766e-4). r19 (desync BT=4) spilled wq to scratch (WRITE_SIZE
// 8KB->30MB, VGPR 128 < demand ~200) and the arithmetic closes the whole
// direction: per-CU MI8 count = 512/BT (16-row tiles can't pack <8
// row-permuted batches), so ANY BT<8 doubles MFMA issue -> >= neutral even
// spill-free.
// CLOSURE LEDGER (why this is the terminal structure):
//  - schedule: r12 optimum; SGB variants r13/r15/r18 all -3% on both dataflows
//  - chain ILP: r14 refuted (co-wave fills dep bubbles, m114)
//  - wave count: r16 halved bank conflicts exactly as predicted, +18% time
//    -> LDS pipe NOT critical; 2-wave co-fill is load-bearing
//  - precision: i8 exact-i32 h-matmul won -11% (r17); fp8/fp4 ~6x worse
//    error (abs 0.5-ulp vs 3-bit mantissa); MX K=128 saves only ~25cy/wave
//  - desync blocks: arithmetic + r19; barrier removal: all-to-all h dep
//  - VALU/trans: 20 trans/wave = algorithmic min (5 act x 2 cells x 2)
// Budget: step 1336cy = 366 MFMA issue + ~430 VALU/trans + ~540 serial
// residue (ds ~120 -> MI8 dep ~80 -> trans chain ~150 -> write/drain/convoy)
// at 60% issue occupancy; 6 mechanisms failed to fill the rest. Latency-
// bound sequential recurrence at its structural limit.
// Structure: 256 blocks x 8 batches, NT=512 (2 waves/SIMD), row-permuted
// direct cell ownership rho(b)=(b>>1)*4+(b&1), dbuf h + 1 barrier/step,
// i8 h-matmul (W*1024, h*127), f16 K=16 x/bias MFMA sc-baked, folded
// activation scales, peeled last step, waves_per_eu(2,2), NO SGBs.

#define HH 128
#define II 5
#define TT 512
#define BT 8
#define NT 512
#define K8S 144            // hb8 row stride in bytes (2-way-free banks, 16-aligned)
#define HB8 (16 * K8S)     // hb8 buffer stride in bytes
#define KS 136             // zrow stride in f16 (x path)
#define XT (TT * 8 + 8)    // xs per-batch stride in f16

typedef __attribute__((ext_vector_type(4))) _Float16 half4;
typedef __attribute__((ext_vector_type(4))) float f32x4;
typedef __attribute__((ext_vector_type(4))) int int4v;

#define SIG(u) __builtin_amdgcn_rcpf(1.0f + __builtin_amdgcn_exp2f(u))
#define MF16(A, B, C) __builtin_amdgcn_mfma_f32_16x16x16f16((A), (B), (C), 0, 0, 0)
#define MI8(A, B, C)  __builtin_amdgcn_mfma_i32_16x16x64_i8((A), (B), (C), 0, 0, 0)

// Recombine scales: arg = xp + S * (sc_g / (1024*127))
#define INV_IFO (-1.44269504f / 130048.0f)
#define INV_G   ( 2.88539008f / 130048.0f)

// One timestep. PB = h read buffer (compile-time 0/1), LAST = peeled final.
#define STEP(PB, LAST) {                                                        \
    const unsigned char* hp = hrd8 + (PB) * HB8;                                \
    int4v alo = *reinterpret_cast<const int4v*>(hp);                            \
    int4v ahi = *reinterpret_cast<const int4v*>(hp + 64);                       \
    /* x/bias projection, f16 K=16, sc-baked (register-only: ds cover) */       \
    f32x4 xp0 = MF16(ax4, wfx[0], zero4);                                       \
    f32x4 xp1 = MF16(ax4, wfx[1], zero4);                                       \
    f32x4 xp2 = MF16(ax4, wfx[2], zero4);                                       \
    f32x4 xp3 = MF16(ax4, wfx[3], zero4);                                       \
    /* i,f i8 chains (K=64 x2, exact i32) */                                    \
    int4v s0 = MI8(alo, wq[0][0], zeroi); int4v s1 = MI8(alo, wq[1][0], zeroi); \
    s0 = MI8(ahi, wq[0][1], s0);          s1 = MI8(ahi, wq[1][1], s1);          \
    /* i,f sigmoids issue while g,o occupy the MFMA pipe (co-wave fill) */      \
    float iv0 = SIG(fmaf((float)s0[0], INV_IFO, xp0[0]));                       \
    float iv1 = SIG(fmaf((float)s0[1], INV_IFO, xp0[1]));                       \
    float fv0 = SIG(fmaf((float)s1[0], INV_IFO, xp1[0]));                       \
    float fv1 = SIG(fmaf((float)s1[1], INV_IFO, xp1[1]));                       \
    /* g,o i8 chains */                                                         \
    int4v s2 = MI8(alo, wq[2][0], zeroi); int4v s3 = MI8(alo, wq[3][0], zeroi); \
    s2 = MI8(ahi, wq[2][1], s2);          s3 = MI8(ahi, wq[3][1], s3);          \
    if (!(LAST)) {                      /* prefetch ax(t+1): static xs */       \
        xcur += xinc;                                                           \
        ax4 = *reinterpret_cast<const half4*>(xcur);                            \
    }                                                                           \
    float gv0 = 1.0f - 2.0f * SIG(fmaf((float)s2[0], INV_G, xp2[0]));           \
    float ov0 = SIG(fmaf((float)s3[0], INV_IFO, xp3[0]));                       \
    cc0 = fv0 * cc0 + iv0 * gv0;                                                \
    float hv0 = ov0 * (1.0f - 2.0f * SIG(2.88539008f * cc0));                   \
    float gv1 = 1.0f - 2.0f * SIG(fmaf((float)s2[1], INV_G, xp2[1]));           \
    float ov1 = SIG(fmaf((float)s3[1], INV_IFO, xp3[1]));                       \
    cc1 = fv1 * cc1 + iv1 * gv1;                                                \
    float hv1 = ov1 * (1.0f - 2.0f * SIG(2.88539008f * cc1));                   \
    if (LAST) {                                                                 \
        hsc[bcell][hcol] = hv0; hsc[bcell + 1][hcol] = hv1;                     \
    } else {                                                                    \
        unsigned char* wp = hwr8 + ((PB) ^ 1) * HB8;                            \
        wp[0]    = (unsigned char)(signed char)(int)rintf(hv0 * 127.0f);        \
        wp[K8S]  = (unsigned char)(signed char)(int)rintf(hv1 * 127.0f);        \
    }                                                                           \
    __syncthreads();                                                            \
}

__global__ __launch_bounds__(NT)
__attribute__((amdgpu_waves_per_eu(2, 2)))   // 256-VGPR budget: spill guard
void lstm_r20(const float* __restrict__ x,      // [B,T,I]
              const float* __restrict__ W_ih,   // [4H,I]
              const float* __restrict__ W_hh,   // [4H,H]
              const float* __restrict__ b_ih,   // [4H]
              const float* __restrict__ b_hh,   // [4H]
              const float* __restrict__ W_lin,  // [H]
              const float* __restrict__ b_lin,  // [1]
              float* __restrict__ out,          // [B]
              int B)
{
    __shared__ __align__(16) unsigned char hb8[2][16][K8S]; // h as i8; pad rows 0
    __shared__ __align__(16) _Float16 zrow[KS];         // zeros for pad-row x lanes
    __shared__ __align__(16) _Float16 xs[BT * XT];      // 65.7 KB staged x (f16)
    __shared__ float hsc[BT][HH + 4];                   // final fp32 h

    const int tid  = threadIdx.x;
    const int b0   = blockIdx.x * BT;
    const int lane = tid & 63;
    const int w    = tid >> 6;        // 0..7 -> col group
    const int n    = lane & 15;       // A row index / D col
    const int q    = lane >> 4;
    const int hcol = w * 16 + n;      // this wave's gate columns

    // ---- W_hh as i8, B-layout: lane holds W^T[k][col n] for k=q*16+e (lo)  --
    // and k=64+q*16+e (hi), e=0..15, packed 4 bytes/i32. scale 1024.
    int4v wq[4][2];                   // [gate][half]
    half4 wfx[4];                     // x/bias f16 chunk, K=16, sc-baked
    #pragma unroll
    for (int g = 0; g < 4; ++g) {
        const float sc = (g == 2) ? 2.88539008f : -1.44269504f;
        const int j = g * HH + hcol;
        #pragma unroll
        for (int half = 0; half < 2; ++half) {
            const float* p = W_hh + (size_t)j * HH + half * 64 + q * 16;
            #pragma unroll
            for (int r = 0; r < 4; ++r) {
                int wd = 0;
                #pragma unroll
                for (int u = 0; u < 4; ++u) {
                    int b = (int)rintf(p[r * 4 + u] * 1024.0f);   // |W|*1024<=91
                    wd |= (b & 0xff) << (8 * u);
                }
                wq[g][half][r] = wd;
            }
        }
        #pragma unroll
        for (int e = 0; e < 4; ++e) {
            const int k = q * 4 + e;
            float v = 0.0f;
            if (k < II)       v = W_ih[j * II + k];
            else if (k == II) v = b_ih[j] + b_hh[j];
            wfx[g][e] = (_Float16)(v * sc);
        }
    }

    // ---- zero LDS -----------------------------------------------------------
    for (int idx = tid; idx < 2 * 16 * K8S; idx += NT)
        (&hb8[0][0][0])[idx] = 0;
    if (tid < KS) zrow[tid] = (_Float16)0.0f;
    for (int idx = tid; idx < BT * XT; idx += NT)
        xs[idx] = (_Float16)0.0f;
    __syncthreads();

    // ---- stage x (f16) + constant-1.0 bias column in slot 5 -----------------
    {
        const int lb = tid & 63, bb = tid >> 6;     // 64 threads per batch
        if (b0 + bb < B) {
            const float* xb = x + (size_t)(b0 + bb) * TT * II;
            for (int e = lb * 4; e < TT * II; e += 256) {
                float4 v = *reinterpret_cast<const float4*>(xb + e);
                float vv[4] = {v.x, v.y, v.z, v.w};
                #pragma unroll
                for (int u = 0; u < 4; ++u) {
                    const int ee = e + u;
                    xs[bb * XT + (ee / 5) * 8 + (ee % 5)] = (_Float16)vv[u];
                }
            }
        }
        for (int s = tid; s < BT * TT; s += NT)
            xs[(s >> 9) * XT + (s & 511) * 8 + 5] = (_Float16)1.0f;
    }
    __syncthreads();

    // ---- loop-invariant state ----------------------------------------------
    // Row permutation (r10): batch b -> A-row rho(b) = (b>>1)*4 + (b&1);
    // C/D rows q*4+{0,1} = batches {2q, 2q+1} -> direct cell ownership.
    const int bcell = 2 * q;
    float cc0 = 0.f, cc1 = 0.f;
    const f32x4 zero4 = {0.f, 0.f, 0.f, 0.f};
    const int4v zeroi = {0, 0, 0, 0};
    const bool xreal = ((n & 2) == 0);
    const int  bofn  = (n >> 2) * 2 + (n & 1);      // batch carried by A-row n
    // A-frag (i8 K=64): lane (n,q) reads h bytes k=q*16+0..15 (lo), +64 (hi).
    // Pad rows (n in {2,3,6,7,...}) stay zero from init -> rows contribute 0.
    const unsigned char* hrd8 = &hb8[0][n][0] + q * 16;
    unsigned char*       hwr8 = &hb8[0][q * 4][0] + hcol;
    // x A-frag (K=16): lane supplies k=q*4+e; garbage at k>=8 multiplies zero
    // W cols -> harmless (verified r11).
    const _Float16* xcur = xreal ? (&xs[bofn * XT] + q * 4) : (&zrow[0] + q * 4);
    const int       xinc = xreal ? 8 : 0;

    half4 ax4 = *reinterpret_cast<const half4*>(xcur);   // t=0 preload

    #pragma unroll 1
    for (int k = 0; k < (TT - 2) / 2; ++k) {
        STEP(0, false);
        STEP(1, false);
    }
    STEP(0, false);     // t = 510
    STEP(1, true);      // t = 511, peeled: fp32 hsc write, no prefetch

    // ---- epilogue: out[b0+w] = hsc[w,:] . W_lin + b_lin ---------------------
    float p = hsc[w][lane] * W_lin[lane] + hsc[w][lane + 64] * W_lin[lane + 64];
    #pragma unroll
    for (int off = 32; off > 0; off >>= 1) p += __shfl_down(p, off, 64);
    if (lane == 0 && (b0 + w) < B) out[b0 + w] = p + b_lin[0];
}

extern "C" void kernel_launch(void* const* d_in, const int* in_sizes, int n_in,
                              void* d_out, int out_size, void* d_ws, size_t ws_size,
                              hipStream_t stream) {
    const float* x     = (const float*)d_in[0];
    const float* W_ih  = (const float*)d_in[1];
    const float* W_hh  = (const float*)d_in[2];
    const float* b_ih  = (const float*)d_in[3];
    const float* b_hh  = (const float*)d_in[4];
    const float* W_lin = (const float*)d_in[5];
    const float* b_lin = (const float*)d_in[6];
    float* out = (float*)d_out;

    const int B = in_sizes[0] / (TT * II);          // 2048
    const int grid = (B + BT - 1) / BT;             // 256 blocks, 1 per CU
    lstm_r20<<<grid, NT, 0, stream>>>(x, W_ih, W_hh, b_ih, b_hh,
                                      W_lin, b_lin, out, B);
}